// Round 22
// baseline (167.093 us; speedup 1.0000x reference)
//
#include <hip/hip_runtime.h>
#include <math.h>

#define B_SZ 8192
#define IN_DIM 1024
#define K_CB 2048
#define D_SZ 256
#define BN_EPS 1e-5f

typedef _Float16 f16;
typedef _Float16 f16x8 __attribute__((ext_vector_type(8)));
typedef _Float16 f16x4 __attribute__((ext_vector_type(4)));
typedef float    f32x4 __attribute__((ext_vector_type(4)));

#define GLOAD_LDS16(g, l) __builtin_amdgcn_global_load_lds(                      \
    (const __attribute__((address_space(1))) unsigned int*)(g),                  \
    (__attribute__((address_space(3))) unsigned int*)(l), 16, 0, 0)

// ---------------------------------------------------------------------------
// f16 MFMA GEMM: C[M,N] = A[M,K] @ B[N,K]^T   (both operands K-contiguous)
// EPI 0: write f32 C           (z = assign @ E^T  via ET)
// EPI 1: write f16 C + bias    (h = x @ W^T  via WT; A is f32, reg-converted)
// ---------------------------------------------------------------------------
template<int BM, int BN, int BK, int EPI, bool A32>
__global__ __launch_bounds__(256) void gemm_mfma(
    const void* __restrict__ Aptr, int lda,
    const f16* __restrict__ Bptr, int ldb,
    void* __restrict__ Cptr, int ldc, int Kdim,
    const float* __restrict__ bias)
{
    constexpr int G    = BK / 8;
    constexpr int MASK = G - 1;
    constexpr int WM = BM / 2, WN = BN / 2;
    constexpr int FM = WM / 16, FN = WN / 16;
    constexpr int CH_A = BM * G;
    constexpr int CH_B = BN * G;

    __shared__ char lds[(BM + BN) * BK * 2];
    char* As = lds;
    char* Bs = lds + BM * BK * 2;

    const int tid  = threadIdx.x;
    const int w    = tid >> 6, lane = tid & 63;
    const int wm   = w >> 1,   wn   = w & 1;
    const int row0 = blockIdx.x * BM;
    const int col0 = blockIdx.y * BN;

    f32x4 acc[FM][FN] = {};

    for (int k0 = 0; k0 < Kdim; k0 += BK) {
        #pragma unroll
        for (int i = 0; i < CH_B / 256; ++i) {
            const int base = (i * 4 + w) * 64;
            const int s = base + lane;
            const int r = s / G, c = s % G;
            const f16* src = Bptr + (size_t)(col0 + r) * ldb + k0 + ((c ^ (r & MASK)) * 8);
            GLOAD_LDS16(src, Bs + base * 16);
        }
        if (!A32) {
            #pragma unroll
            for (int i = 0; i < CH_A / 256; ++i) {
                const int base = (i * 4 + w) * 64;
                const int s = base + lane;
                const int r = s / G, c = s % G;
                const f16* src = (const f16*)Aptr + (size_t)(row0 + r) * lda + k0 + ((c ^ (r & MASK)) * 8);
                GLOAD_LDS16(src, As + base * 16);
            }
        } else {
            #pragma unroll
            for (int i = 0; i < CH_A / 256; ++i) {
                const int s = i * 256 + tid;
                const int r = s / G, c = s % G;
                const float* src = (const float*)Aptr + (size_t)(row0 + r) * lda + k0 + c * 8;
                const float4 v0 = ((const float4*)src)[0];
                const float4 v1 = ((const float4*)src)[1];
                f16x8 d;
                d[0] = (f16)v0.x; d[1] = (f16)v0.y; d[2] = (f16)v0.z; d[3] = (f16)v0.w;
                d[4] = (f16)v1.x; d[5] = (f16)v1.y; d[6] = (f16)v1.z; d[7] = (f16)v1.w;
                *(f16x8*)(As + (r * G + (c ^ (r & MASK))) * 16) = d;
            }
        }
        __syncthreads();

        #pragma unroll
        for (int kk = 0; kk < BK / 32; ++kk) {
            f16x8 af[FM], bf[FN];
            #pragma unroll
            for (int m = 0; m < FM; ++m) {
                const int r = wm * WM + m * 16 + (lane & 15);
                const int g = (kk * 4 + (lane >> 4)) ^ (r & MASK);
                af[m] = *(const f16x8*)(As + r * (BK * 2) + g * 16);
            }
            #pragma unroll
            for (int n = 0; n < FN; ++n) {
                const int r = wn * WN + n * 16 + (lane & 15);
                const int g = (kk * 4 + (lane >> 4)) ^ (r & MASK);
                bf[n] = *(const f16x8*)(Bs + r * (BK * 2) + g * 16);
            }
            #pragma unroll
            for (int m = 0; m < FM; ++m)
                #pragma unroll
                for (int n = 0; n < FN; ++n)
                    acc[m][n] = __builtin_amdgcn_mfma_f32_16x16x32_f16(af[m], bf[n], acc[m][n], 0, 0, 0);
        }
        __syncthreads();
    }

    #pragma unroll
    for (int m = 0; m < FM; ++m) {
        const int rbase = row0 + wm * WM + m * 16 + (lane >> 4) * 4;
        #pragma unroll
        for (int n = 0; n < FN; ++n) {
            const int c = col0 + wn * WN + n * 16 + (lane & 15);
            #pragma unroll
            for (int j = 0; j < 4; ++j) {
                const float v = acc[m][n][j];
                if (EPI == 0) {
                    ((float*)Cptr)[(size_t)(rbase + j) * ldc + c] = v;
                } else {
                    ((f16*)Cptr)[(size_t)(rbase + j) * ldc + c] = (f16)(v + bias[c]);
                }
            }
        }
    }
}

// ---------------------------------------------------------------------------
// Fused: logits-GEMM + dual softmax. (R21 structure; af re-loaded per chunk)
// 32 rows/block, 1024 threads = 16 waves, 256 blocks = ONE round.
// E staged via double-buffered 2x64KB (aliased into p1 buffer).
// Per chunk: af loads (8, from L2-resident normalized h16; opaque-zero offset
// defeats LICM/GVN) -> staging (4) -> vmcnt(4): FIFO completes af + chunk-c
// stage, keeps chunk-c+1 stage in flight. Persistent regs = acc[16] only.
// p1 = exp(l - m1 + 10) f16, stride 2056. No m2. Tail keeps gv as f16.
// ---------------------------------------------------------------------------
#define LP1 2056   // p1 row stride (f16)

__global__ __launch_bounds__(1024, 1) void fused_sm(
    const f16* __restrict__ h16, const f16* __restrict__ E16,
    const float* __restrict__ e2v, const float* __restrict__ u,
    float* __restrict__ probs, f16* __restrict__ assign16)
{
    __shared__ __align__(16) char lds_raw[32 * LP1 * 2];   // 131584B
    __shared__ float redA[16 * 16];
    f16* Bs0 = (f16*)lds_raw;                  // E-stage buf 0 (64KB)
    f16* Bs1 = Bs0 + 128 * 256;                // E-stage buf 1 (64KB)
    f16* p1buf = (f16*)lds_raw;                // after GEMM: p1 [32][LP1]

    const int tid  = threadIdx.x;
    const int w    = tid >> 6, lane = tid & 63;
    const int q    = lane >> 4, r16 = lane & 15;
    const int g2   = w >> 3;                   // row-group 0/1
    const int wc   = w & 7;                    // col strip
    const int row0 = blockIdx.x * 32;
    const int rowA = row0 + g2 * 16;           // this wave's 16-row base
    const int colL = wc * 16 + r16;            // col within a 128-col chunk

    const f16* hrow = h16 + (size_t)(rowA + r16) * D_SZ + q * 8;

    f32x4 acc[16];
    #pragma unroll
    for (int n = 0; n < 16; ++n) acc[n] = (f32x4){0.f, 0.f, 0.f, 0.f};

    // prologue: stage chunk 0 (4096 granules / 1024 thr = 4 each)
    #pragma unroll
    for (int i = 0; i < 4; ++i) {
        const int base = (i * 16 + w) * 64;
        const int s = base + lane;
        const int r = s >> 5, cgg = s & 31;
        GLOAD_LDS16(E16 + (size_t)r * D_SZ + ((cgg ^ (r & 31)) * 8), Bs0 + base * 8);
    }

    // ---- GEMM over 16 chunks of 128 E-rows, double-buffered counted-vmcnt
    #pragma unroll
    for (int c = 0; c < 16; ++c) {
        f16* buf  = (c & 1) ? Bs1 : Bs0;
        f16* nbuf = (c & 1) ? Bs0 : Bs1;

        // af loads FIRST (oldest in vmem FIFO); opaque zero defeats hoisting
        int zz;
        asm volatile("v_mov_b32 %0, 0" : "=v"(zz));
        f16x8 af[8];
        #pragma unroll
        for (int kk = 0; kk < 8; ++kk)
            af[kk] = *(const f16x8*)(hrow + kk * 32 + zz);

        if (c < 15) {
            #pragma unroll
            for (int i = 0; i < 4; ++i) {
                const int base = (i * 16 + w) * 64;
                const int s = base + lane;
                const int r = s >> 5, cgg = s & 31;
                GLOAD_LDS16(E16 + (size_t)((c + 1) * 128 + r) * D_SZ + ((cgg ^ (r & 31)) * 8),
                            nbuf + base * 8);
            }
            // FIFO: completes af(8) + chunk-c stage(4); chunk-c+1 stage stays out
            asm volatile("s_waitcnt vmcnt(4)" ::: "memory");
        } else {
            asm volatile("s_waitcnt vmcnt(0)" ::: "memory");
        }
        __builtin_amdgcn_s_barrier();
        __builtin_amdgcn_sched_barrier(0);
        #pragma unroll
        for (int kk = 0; kk < 8; ++kk) {
            const int gb = (kk * 4 + q) ^ (colL & 31);
            const f16x8 bf = *(const f16x8*)(buf + colL * 256 + gb * 8);
            acc[c] = __builtin_amdgcn_mfma_f32_16x16x32_f16(af[kk], bf, acc[c], 0, 0, 0);
        }
        __builtin_amdgcn_sched_barrier(0);
        __builtin_amdgcn_s_barrier();
        __builtin_amdgcn_sched_barrier(0);
    }
    __syncthreads();   // all MFMA reads done; LDS free for p1

    // ---- m1 reduction (per row-group, rows q*4+j)
    float m1[4] = {-1e30f, -1e30f, -1e30f, -1e30f};
    #pragma unroll
    for (int n = 0; n < 16; ++n) {
        const float ec = e2v[n * 128 + colL];
        #pragma unroll
        for (int j = 0; j < 4; ++j)
            m1[j] = fmaxf(m1[j], 2.f * acc[n][j] - ec);
    }
    #pragma unroll
    for (int off = 1; off < 16; off <<= 1)
        #pragma unroll
        for (int j = 0; j < 4; ++j)
            m1[j] = fmaxf(m1[j], __shfl_xor(m1[j], off));
    if (r16 == 0)
        #pragma unroll
        for (int j = 0; j < 4; ++j) redA[w * 16 + q * 4 + j] = m1[j];
    __syncthreads();
    #pragma unroll
    for (int j = 0; j < 4; ++j) {
        float a = -1e30f;
        #pragma unroll
        for (int t = 0; t < 8; ++t) a = fmaxf(a, redA[(g2 * 8 + t) * 16 + q * 4 + j]);
        m1[j] = a;
    }

    // ---- p1 = exp(l - m1 + 10) as f16 into LDS (bias cancels in norms)
    #pragma unroll
    for (int n = 0; n < 16; ++n) {
        const float ec = e2v[n * 128 + colL];
        #pragma unroll
        for (int j = 0; j < 4; ++j) {
            const float lv = 2.f * acc[n][j] - ec;
            p1buf[(size_t)(g2 * 16 + q * 4 + j) * LP1 + n * 128 + colL] =
                (f16)__expf(lv - m1[j] + 10.f);
        }
    }
    __syncthreads();

    // ---- coalesced tail: thread owns row tid>>5 (0..31), cols (tid&31)*4+n*128
    const int trow = tid >> 5;
    const int cg   = tid & 31;
    const float* urow = u + (size_t)(row0 + trow) * K_CB + cg * 4;
    const f16* prow_l = p1buf + (size_t)trow * LP1 + cg * 4;

    float s1 = 0.f, s2 = 0.f;
    f16x4 gv[16];                      // gumbel g as f16 (range <= 16.6)
    #pragma unroll
    for (int n = 0; n < 16; ++n) {
        const float4 u4 = *(const float4*)(urow + n * 128);
        const f16x4 p4 = *(const f16x4*)(prow_l + n * 128);
        const float ua[4] = {u4.x, u4.y, u4.z, u4.w};
        #pragma unroll
        for (int e = 0; e < 4; ++e) {
            const f16 g = (f16)(-__logf(-__logf(ua[e] + 1e-10f) + 1e-10f));
            gv[n][e] = g;
            s1 += (float)p4[e];
            s2 += (float)p4[e] * __expf((float)g);
        }
    }
    #pragma unroll
    for (int off = 1; off < 32; off <<= 1) {
        s1 += __shfl_xor(s1, off);
        s2 += __shfl_xor(s2, off);
    }
    const float r1 = 1.f / s1;
    const float r2 = 1.f / s2;

    float* prow = probs + (size_t)(row0 + trow) * K_CB + cg * 4;
    f16* arow = assign16 + (size_t)(row0 + trow) * K_CB + cg * 4;
    #pragma unroll
    for (int n = 0; n < 16; ++n) {
        const f16x4 p4 = *(const f16x4*)(prow_l + n * 128);
        float4 o;
        o.x = (float)p4[0] * r1; o.y = (float)p4[1] * r1;
        o.z = (float)p4[2] * r1; o.w = (float)p4[3] * r1;
        *(float4*)(prow + n * 128) = o;
        f16x4 a4;
        #pragma unroll
        for (int e = 0; e < 4; ++e)
            a4[e] = (f16)((float)p4[e] * __expf((float)gv[n][e]) * r2);
        *(f16x4*)(arow + n * 128) = a4;
    }
}

// ---------------------------------------------------------------------------
// Tiled transpose f32 -> f16 (R21): dstT[C][R] = (f16)src[R][C]; optional
// direct copy. 64x64 tiles via LDS (stride 66); coalesced on both sides.
// ---------------------------------------------------------------------------
template<bool DIRECT>
__global__ __launch_bounds__(256) void transp_f16(
    const float* __restrict__ src, f16* __restrict__ dstT, f16* __restrict__ dst,
    int R, int C)
{
    __shared__ f16 tile[64][66];
    const int tr = blockIdx.x * 64, tc = blockIdx.y * 64;
    const int lr = threadIdx.x >> 4;
    const int lc = (threadIdx.x & 15) * 4;

    #pragma unroll
    for (int i = 0; i < 4; ++i) {
        const int row = i * 16 + lr;
        const float4 v = *(const float4*)(src + (size_t)(tr + row) * C + tc + lc);
        f16 h0 = (f16)v.x, h1 = (f16)v.y, h2 = (f16)v.z, h3 = (f16)v.w;
        tile[row][lc + 0] = h0; tile[row][lc + 1] = h1;
        tile[row][lc + 2] = h2; tile[row][lc + 3] = h3;
        if (DIRECT) {
            f16x4 d; d[0] = h0; d[1] = h1; d[2] = h2; d[3] = h3;
            *(f16x4*)(dst + (size_t)(tr + row) * C + tc + lc) = d;
        }
    }
    __syncthreads();
    #pragma unroll
    for (int i = 0; i < 4; ++i) {
        const int drow = i * 16 + lr;
        f16x4 o;
        o[0] = tile[lc + 0][drow]; o[1] = tile[lc + 1][drow];
        o[2] = tile[lc + 2][drow]; o[3] = tile[lc + 3][drow];
        *(f16x4*)(dstT + (size_t)(tc + drow) * R + tr + lc) = o;
    }
}

// ---------------- codebook row norms (f32 E, coalesced) ----------------
__global__ __launch_bounds__(256) void e2_kernel(const float* __restrict__ E, float* __restrict__ e2)
{
    const int wave = threadIdx.x >> 6, lane = threadIdx.x & 63;
    const int row = blockIdx.x * 4 + wave;
    const float4 v = ((const float4*)(E + (size_t)row * D_SZ))[lane];
    float ss = v.x * v.x + v.y * v.y + v.z * v.z + v.w * v.w;
    #pragma unroll
    for (int off = 32; off > 0; off >>= 1) ss += __shfl_down(ss, off);
    if (lane == 0) e2[row] = ss;
}

// ---------------- BN batch stats (two-stage, deterministic) ----------------
__global__ __launch_bounds__(256) void bn_partial(const f16* __restrict__ h16, float* __restrict__ part)
{
    const int d = threadIdx.x;
    const int blk = blockIdx.x;                 // 128 blocks x 64 rows
    const int r0 = blk * (B_SZ / 128);
    float s = 0.f, sq = 0.f;
    for (int r = r0; r < r0 + (B_SZ / 128); ++r) {
        const float v = (float)h16[(size_t)r * D_SZ + d];
        s += v; sq += v * v;
    }
    part[blk * 512 + d]       = s;
    part[blk * 512 + 256 + d] = sq;
}

__global__ __launch_bounds__(256) void bn_finalize(
    const float* __restrict__ part, const float* __restrict__ gamma, const float* __restrict__ beta,
    float* __restrict__ scale, float* __restrict__ shift)
{
    const int d = threadIdx.x;
    float s = 0.f, sq = 0.f;
    for (int b = 0; b < 128; ++b) { s += part[b * 512 + d]; sq += part[b * 512 + 256 + d]; }
    const float mu  = s / (float)B_SZ;
    const float var = sq / (float)B_SZ - mu * mu;
    const float sc  = gamma[d] * rsqrtf(var + BN_EPS);
    scale[d] = sc;
    shift[d] = beta[d] - mu * sc;
}

// ---------------- normalize h16 in place ----------------
__global__ __launch_bounds__(256) void norm_h(
    f16* __restrict__ h16, const float* __restrict__ scale, const float* __restrict__ shift)
{
    const int wave = threadIdx.x >> 6, lane = threadIdx.x & 63;
    const int row = blockIdx.x * 4 + wave;
    f16x4* hp = (f16x4*)(h16 + (size_t)row * D_SZ);
    f16x4 v = hp[lane];
    const float4 sc = ((const float4*)scale)[lane];
    const float4 sh = ((const float4*)shift)[lane];
    v[0] = (f16)fmaf((float)v[0], sc.x, sh.x);
    v[1] = (f16)fmaf((float)v[1], sc.y, sh.y);
    v[2] = (f16)fmaf((float)v[2], sc.z, sh.z);
    v[3] = (f16)fmaf((float)v[3], sc.w, sh.w);
    hp[lane] = v;
}

extern "C" void kernel_launch(void* const* d_in, const int* in_sizes, int n_in,
                              void* d_out, int out_size, void* d_ws, size_t ws_size,
                              hipStream_t stream)
{
    const float* x     = (const float*)d_in[0];
    const float* u     = (const float*)d_in[1];
    const float* W     = (const float*)d_in[2];
    const float* bias  = (const float*)d_in[3];
    const float* gamma = (const float*)d_in[4];
    const float* beta  = (const float*)d_in[5];
    const float* E     = (const float*)d_in[6];

    float* probs = (float*)d_out;                       // [B, K] f32
    float* z     = probs + (size_t)B_SZ * K_CB;         // [B, D] f32

    char* ws = (char*)d_ws;
    f16* assign16 = (f16*)ws;  ws += (size_t)B_SZ * K_CB * 2;     // 32MB
    f16* h16 = (f16*)ws;       ws += (size_t)B_SZ * D_SZ * 2;     // 4MB
    f16* WT16 = (f16*)ws;      ws += (size_t)D_SZ * IN_DIM * 2;   // 0.5MB
    f16* E16 = (f16*)ws;       ws += (size_t)K_CB * D_SZ * 2;     // 1MB
    f16* ET16 = (f16*)ws;      ws += (size_t)D_SZ * K_CB * 2;     // 1MB
    float* part = (float*)ws;  ws += 128 * 512 * 4;
    float* scale = (float*)ws; ws += D_SZ * 4;
    float* shift = (float*)ws; ws += D_SZ * 4;
    float* e2 = (float*)ws;    ws += K_CB * 4;

    // prep: tiled-transpose f16 operands (coalesced both sides) + norms
    {
        dim3 gW(IN_DIM / 64, D_SZ / 64);     // W [1024][256] -> WT16 [256][1024]
        transp_f16<false><<<gW, 256, 0, stream>>>(W, WT16, nullptr, IN_DIM, D_SZ);
        dim3 gE(K_CB / 64, D_SZ / 64);       // E [2048][256] -> ET16 [256][2048] + E16
        transp_f16<true><<<gE, 256, 0, stream>>>(E, ET16, E16, K_CB, D_SZ);
    }
    e2_kernel<<<K_CB / 4, 256, 0, stream>>>(E, e2);

    // 1) h16 = f16(x @ W + b)  (raw, pre-BN)   M=8192 N=256 K=1024
    {
        dim3 g(B_SZ / 64, D_SZ / 64);
        gemm_mfma<64, 64, 64, 1, true><<<g, 256, 0, stream>>>(
            x, IN_DIM, WT16, IN_DIM, h16, D_SZ, IN_DIM, bias);
    }
    // 2) BN stats -> scale/shift; normalize h16 in place
    bn_partial<<<128, 256, 0, stream>>>(h16, part);
    bn_finalize<<<1, 256, 0, stream>>>(part, gamma, beta, scale, shift);
    norm_h<<<B_SZ / 4, 256, 0, stream>>>(h16, scale, shift);

    // 3) fused logits-GEMM + dual softmax -> probs (f32) + assign (f16)
    fused_sm<<<B_SZ / 32, 1024, 0, stream>>>(h16, E16, e2, u, probs, assign16);

    // 4) z = assign @ E                   M=8192 N=256 K=2048, 512 blocks
    {
        dim3 g(B_SZ / 64, D_SZ / 64);
        gemm_mfma<64, 64, 128, 0, false><<<g, 256, 0, stream>>>(
            assign16, K_CB, ET16, K_CB, z, D_SZ, K_CB, nullptr);
    }
}

// Round 23
// 115.848 us; speedup vs baseline: 1.4423x; 1.4423x over previous
//
#include <hip/hip_runtime.h>
#include <math.h>

#define B_SZ 8192
#define IN_DIM 1024
#define K_CB 2048
#define D_SZ 256
#define BN_EPS 1e-5f

typedef _Float16 f16;
typedef _Float16 f16x8 __attribute__((ext_vector_type(8)));
typedef _Float16 f16x4 __attribute__((ext_vector_type(4)));
typedef float    f32x4 __attribute__((ext_vector_type(4)));

#define GLOAD_LDS16(g, l) __builtin_amdgcn_global_load_lds(                      \
    (const __attribute__((address_space(1))) unsigned int*)(g),                  \
    (__attribute__((address_space(3))) unsigned int*)(l), 16, 0, 0)

// ---------------------------------------------------------------------------
// f16 MFMA GEMM: C[M,N] = A[M,K] @ B[N,K]^T   (both operands K-contiguous)
// EPI 0: write f32 C           (z = assign @ E^T  via ET)
// EPI 1: write f16 C + bias    (h = x @ W^T  via WT; A is f32, reg-converted)
// ---------------------------------------------------------------------------
template<int BM, int BN, int BK, int EPI, bool A32>
__global__ __launch_bounds__(256) void gemm_mfma(
    const void* __restrict__ Aptr, int lda,
    const f16* __restrict__ Bptr, int ldb,
    void* __restrict__ Cptr, int ldc, int Kdim,
    const float* __restrict__ bias)
{
    constexpr int G    = BK / 8;
    constexpr int MASK = G - 1;
    constexpr int WM = BM / 2, WN = BN / 2;
    constexpr int FM = WM / 16, FN = WN / 16;
    constexpr int CH_A = BM * G;
    constexpr int CH_B = BN * G;

    __shared__ char lds[(BM + BN) * BK * 2];
    char* As = lds;
    char* Bs = lds + BM * BK * 2;

    const int tid  = threadIdx.x;
    const int w    = tid >> 6, lane = tid & 63;
    const int wm   = w >> 1,   wn   = w & 1;
    const int row0 = blockIdx.x * BM;
    const int col0 = blockIdx.y * BN;

    f32x4 acc[FM][FN] = {};

    for (int k0 = 0; k0 < Kdim; k0 += BK) {
        #pragma unroll
        for (int i = 0; i < CH_B / 256; ++i) {
            const int base = (i * 4 + w) * 64;
            const int s = base + lane;
            const int r = s / G, c = s % G;
            const f16* src = Bptr + (size_t)(col0 + r) * ldb + k0 + ((c ^ (r & MASK)) * 8);
            GLOAD_LDS16(src, Bs + base * 16);
        }
        if (!A32) {
            #pragma unroll
            for (int i = 0; i < CH_A / 256; ++i) {
                const int base = (i * 4 + w) * 64;
                const int s = base + lane;
                const int r = s / G, c = s % G;
                const f16* src = (const f16*)Aptr + (size_t)(row0 + r) * lda + k0 + ((c ^ (r & MASK)) * 8);
                GLOAD_LDS16(src, As + base * 16);
            }
        } else {
            #pragma unroll
            for (int i = 0; i < CH_A / 256; ++i) {
                const int s = i * 256 + tid;
                const int r = s / G, c = s % G;
                const float* src = (const float*)Aptr + (size_t)(row0 + r) * lda + k0 + c * 8;
                const float4 v0 = ((const float4*)src)[0];
                const float4 v1 = ((const float4*)src)[1];
                f16x8 d;
                d[0] = (f16)v0.x; d[1] = (f16)v0.y; d[2] = (f16)v0.z; d[3] = (f16)v0.w;
                d[4] = (f16)v1.x; d[5] = (f16)v1.y; d[6] = (f16)v1.z; d[7] = (f16)v1.w;
                *(f16x8*)(As + (r * G + (c ^ (r & MASK))) * 16) = d;
            }
        }
        __syncthreads();

        #pragma unroll
        for (int kk = 0; kk < BK / 32; ++kk) {
            f16x8 af[FM], bf[FN];
            #pragma unroll
            for (int m = 0; m < FM; ++m) {
                const int r = wm * WM + m * 16 + (lane & 15);
                const int g = (kk * 4 + (lane >> 4)) ^ (r & MASK);
                af[m] = *(const f16x8*)(As + r * (BK * 2) + g * 16);
            }
            #pragma unroll
            for (int n = 0; n < FN; ++n) {
                const int r = wn * WN + n * 16 + (lane & 15);
                const int g = (kk * 4 + (lane >> 4)) ^ (r & MASK);
                bf[n] = *(const f16x8*)(Bs + r * (BK * 2) + g * 16);
            }
            #pragma unroll
            for (int m = 0; m < FM; ++m)
                #pragma unroll
                for (int n = 0; n < FN; ++n)
                    acc[m][n] = __builtin_amdgcn_mfma_f32_16x16x32_f16(af[m], bf[n], acc[m][n], 0, 0, 0);
        }
        __syncthreads();
    }

    #pragma unroll
    for (int m = 0; m < FM; ++m) {
        const int rbase = row0 + wm * WM + m * 16 + (lane >> 4) * 4;
        #pragma unroll
        for (int n = 0; n < FN; ++n) {
            const int c = col0 + wn * WN + n * 16 + (lane & 15);
            #pragma unroll
            for (int j = 0; j < 4; ++j) {
                const float v = acc[m][n][j];
                if (EPI == 0) {
                    ((float*)Cptr)[(size_t)(rbase + j) * ldc + c] = v;
                } else {
                    ((f16*)Cptr)[(size_t)(rbase + j) * ldc + c] = (f16)(v + bias[c]);
                }
            }
        }
    }
}

// ---------------------------------------------------------------------------
// Fused: BN (folded into A-load) + logits-GEMM + dual softmax.
// 32 rows/block, 1024 threads = 16 waves, 256 blocks = ONE round.
// E staged via double-buffered 2x64KB (aliased into p1 buffer); vmcnt(4).
// p1 = exp(l - m1 + 10) f16, stride 2056. No m2. Tail keeps gv as f16.
// ---------------------------------------------------------------------------
#define LP1 2056   // p1 row stride (f16)

__global__ __launch_bounds__(1024, 1) void fused_sm(
    const f16* __restrict__ h16, const f16* __restrict__ E16,
    const float* __restrict__ e2v, const float* __restrict__ u,
    const float* __restrict__ scale, const float* __restrict__ shift,
    float* __restrict__ probs, f16* __restrict__ assign16)
{
    __shared__ __align__(16) char lds_raw[32 * LP1 * 2];   // 131584B
    __shared__ float redA[16 * 16];
    f16* Bs0 = (f16*)lds_raw;                  // E-stage buf 0 (64KB)
    f16* Bs1 = Bs0 + 128 * 256;                // E-stage buf 1 (64KB)
    f16* p1buf = (f16*)lds_raw;                // after GEMM: p1 [32][LP1]

    const int tid  = threadIdx.x;
    const int w    = tid >> 6, lane = tid & 63;
    const int q    = lane >> 4, r16 = lane & 15;
    const int g2   = w >> 3;                   // row-group 0/1
    const int wc   = w & 7;                    // col strip
    const int row0 = blockIdx.x * 32;
    const int rowA = row0 + g2 * 16;           // this wave's 16-row base
    const int colL = wc * 16 + r16;            // col within a 128-col chunk

    // ---- A fragments: 16 rows x K=256 from raw h16, BN applied in f32
    f16x8 af[8];
    {
        const f16* hrow = h16 + (size_t)(rowA + r16) * D_SZ + q * 8;
        #pragma unroll
        for (int kk = 0; kk < 8; ++kk) {
            const f16x8 raw = *(const f16x8*)(hrow + kk * 32);
            const float4 scA = *(const float4*)(scale + kk * 32 + q * 8);
            const float4 scB = *(const float4*)(scale + kk * 32 + q * 8 + 4);
            const float4 shA = *(const float4*)(shift + kk * 32 + q * 8);
            const float4 shB = *(const float4*)(shift + kk * 32 + q * 8 + 4);
            f16x8 d;
            d[0] = (f16)fmaf((float)raw[0], scA.x, shA.x);
            d[1] = (f16)fmaf((float)raw[1], scA.y, shA.y);
            d[2] = (f16)fmaf((float)raw[2], scA.z, shA.z);
            d[3] = (f16)fmaf((float)raw[3], scA.w, shA.w);
            d[4] = (f16)fmaf((float)raw[4], scB.x, shB.x);
            d[5] = (f16)fmaf((float)raw[5], scB.y, shB.y);
            d[6] = (f16)fmaf((float)raw[6], scB.z, shB.z);
            d[7] = (f16)fmaf((float)raw[7], scB.w, shB.w);
            af[kk] = d;
        }
    }

    f32x4 acc[16];
    #pragma unroll
    for (int n = 0; n < 16; ++n) acc[n] = (f32x4){0.f, 0.f, 0.f, 0.f};

    // prologue: stage chunk 0 (4096 granules / 1024 thr = 4 each)
    #pragma unroll
    for (int i = 0; i < 4; ++i) {
        const int base = (i * 16 + w) * 64;
        const int s = base + lane;
        const int r = s >> 5, cgg = s & 31;
        GLOAD_LDS16(E16 + (size_t)r * D_SZ + ((cgg ^ (r & 31)) * 8), Bs0 + base * 8);
    }

    // ---- GEMM over 16 chunks of 128 E-rows, double-buffered counted-vmcnt
    #pragma unroll
    for (int c = 0; c < 16; ++c) {
        f16* buf  = (c & 1) ? Bs1 : Bs0;
        f16* nbuf = (c & 1) ? Bs0 : Bs1;
        if (c < 15) {
            #pragma unroll
            for (int i = 0; i < 4; ++i) {
                const int base = (i * 16 + w) * 64;
                const int s = base + lane;
                const int r = s >> 5, cgg = s & 31;
                GLOAD_LDS16(E16 + (size_t)((c + 1) * 128 + r) * D_SZ + ((cgg ^ (r & 31)) * 8),
                            nbuf + base * 8);
            }
            asm volatile("s_waitcnt vmcnt(4)" ::: "memory");
        } else {
            asm volatile("s_waitcnt vmcnt(0)" ::: "memory");
        }
        __builtin_amdgcn_s_barrier();
        __builtin_amdgcn_sched_barrier(0);
        #pragma unroll
        for (int kk = 0; kk < 8; ++kk) {
            const int gb = (kk * 4 + q) ^ (colL & 31);
            const f16x8 bf = *(const f16x8*)(buf + colL * 256 + gb * 8);
            acc[c] = __builtin_amdgcn_mfma_f32_16x16x32_f16(af[kk], bf, acc[c], 0, 0, 0);
        }
        __builtin_amdgcn_sched_barrier(0);
        __builtin_amdgcn_s_barrier();
        __builtin_amdgcn_sched_barrier(0);
    }
    __syncthreads();   // all MFMA reads done; LDS free for p1

    // ---- m1 reduction (per row-group, rows q*4+j)
    float m1[4] = {-1e30f, -1e30f, -1e30f, -1e30f};
    #pragma unroll
    for (int n = 0; n < 16; ++n) {
        const float ec = e2v[n * 128 + colL];
        #pragma unroll
        for (int j = 0; j < 4; ++j)
            m1[j] = fmaxf(m1[j], 2.f * acc[n][j] - ec);
    }
    #pragma unroll
    for (int off = 1; off < 16; off <<= 1)
        #pragma unroll
        for (int j = 0; j < 4; ++j)
            m1[j] = fmaxf(m1[j], __shfl_xor(m1[j], off));
    if (r16 == 0)
        #pragma unroll
        for (int j = 0; j < 4; ++j) redA[w * 16 + q * 4 + j] = m1[j];
    __syncthreads();
    #pragma unroll
    for (int j = 0; j < 4; ++j) {
        float a = -1e30f;
        #pragma unroll
        for (int t = 0; t < 8; ++t) a = fmaxf(a, redA[(g2 * 8 + t) * 16 + q * 4 + j]);
        m1[j] = a;
    }

    // ---- p1 = exp(l - m1 + 10) as f16 into LDS (bias cancels in norms)
    #pragma unroll
    for (int n = 0; n < 16; ++n) {
        const float ec = e2v[n * 128 + colL];
        #pragma unroll
        for (int j = 0; j < 4; ++j) {
            const float lv = 2.f * acc[n][j] - ec;
            p1buf[(size_t)(g2 * 16 + q * 4 + j) * LP1 + n * 128 + colL] =
                (f16)__expf(lv - m1[j] + 10.f);
        }
    }
    __syncthreads();

    // ---- coalesced tail: thread owns row tid>>5 (0..31), cols (tid&31)*4+n*128
    const int trow = tid >> 5;
    const int cg   = tid & 31;
    const float* urow = u + (size_t)(row0 + trow) * K_CB + cg * 4;
    const f16* prow_l = p1buf + (size_t)trow * LP1 + cg * 4;

    float s1 = 0.f, s2 = 0.f;
    f16x4 gv[16];                      // gumbel g as f16 (range <= 16.6)
    #pragma unroll
    for (int n = 0; n < 16; ++n) {
        const float4 u4 = *(const float4*)(urow + n * 128);
        const f16x4 p4 = *(const f16x4*)(prow_l + n * 128);
        const float ua[4] = {u4.x, u4.y, u4.z, u4.w};
        #pragma unroll
        for (int e = 0; e < 4; ++e) {
            const f16 g = (f16)(-__logf(-__logf(ua[e] + 1e-10f) + 1e-10f));
            gv[n][e] = g;
            s1 += (float)p4[e];
            s2 += (float)p4[e] * __expf((float)g);
        }
    }
    #pragma unroll
    for (int off = 1; off < 32; off <<= 1) {
        s1 += __shfl_xor(s1, off);
        s2 += __shfl_xor(s2, off);
    }
    const float r1 = 1.f / s1;
    const float r2 = 1.f / s2;

    float* prow = probs + (size_t)(row0 + trow) * K_CB + cg * 4;
    f16* arow = assign16 + (size_t)(row0 + trow) * K_CB + cg * 4;
    #pragma unroll
    for (int n = 0; n < 16; ++n) {
        const f16x4 p4 = *(const f16x4*)(prow_l + n * 128);
        float4 o;
        o.x = (float)p4[0] * r1; o.y = (float)p4[1] * r1;
        o.z = (float)p4[2] * r1; o.w = (float)p4[3] * r1;
        *(float4*)(prow + n * 128) = o;
        f16x4 a4;
        #pragma unroll
        for (int e = 0; e < 4; ++e)
            a4[e] = (f16)((float)p4[e] * __expf((float)gv[n][e]) * r2);
        *(f16x4*)(arow + n * 128) = a4;
    }
}

// ---------------------------------------------------------------------------
// Tiled transpose f32 -> f16: dstT[C][R] = (f16)src[R][C]; optional direct
// copy. 64x64 tiles via LDS (stride 66); coalesced on both global sides.
// ---------------------------------------------------------------------------
template<bool DIRECT>
__global__ __launch_bounds__(256) void transp_f16(
    const float* __restrict__ src, f16* __restrict__ dstT, f16* __restrict__ dst,
    int R, int C)
{
    __shared__ f16 tile[64][66];
    const int tr = blockIdx.x * 64, tc = blockIdx.y * 64;
    const int lr = threadIdx.x >> 4;
    const int lc = (threadIdx.x & 15) * 4;

    #pragma unroll
    for (int i = 0; i < 4; ++i) {
        const int row = i * 16 + lr;
        const float4 v = *(const float4*)(src + (size_t)(tr + row) * C + tc + lc);
        f16 h0 = (f16)v.x, h1 = (f16)v.y, h2 = (f16)v.z, h3 = (f16)v.w;
        tile[row][lc + 0] = h0; tile[row][lc + 1] = h1;
        tile[row][lc + 2] = h2; tile[row][lc + 3] = h3;
        if (DIRECT) {
            f16x4 d; d[0] = h0; d[1] = h1; d[2] = h2; d[3] = h3;
            *(f16x4*)(dst + (size_t)(tr + row) * C + tc + lc) = d;
        }
    }
    __syncthreads();
    #pragma unroll
    for (int i = 0; i < 4; ++i) {
        const int drow = i * 16 + lr;
        f16x4 o;
        o[0] = tile[lc + 0][drow]; o[1] = tile[lc + 1][drow];
        o[2] = tile[lc + 2][drow]; o[3] = tile[lc + 3][drow];
        *(f16x4*)(dstT + (size_t)(tc + drow) * R + tr + lc) = o;
    }
}

// ---------------- codebook row norms (f32 E, coalesced) ----------------
__global__ __launch_bounds__(256) void e2_kernel(const float* __restrict__ E, float* __restrict__ e2)
{
    const int wave = threadIdx.x >> 6, lane = threadIdx.x & 63;
    const int row = blockIdx.x * 4 + wave;
    const float4 v = ((const float4*)(E + (size_t)row * D_SZ))[lane];
    float ss = v.x * v.x + v.y * v.y + v.z * v.z + v.w * v.w;
    #pragma unroll
    for (int off = 32; off > 0; off >>= 1) ss += __shfl_down(ss, off);
    if (lane == 0) e2[row] = ss;
}

// ---------------- BN batch stats (two-stage, deterministic) ----------------
__global__ __launch_bounds__(256) void bn_partial(const f16* __restrict__ h16, float* __restrict__ part)
{
    const int d = threadIdx.x;
    const int blk = blockIdx.x;                 // 128 blocks x 64 rows
    const int r0 = blk * (B_SZ / 128);
    float s = 0.f, sq = 0.f;
    for (int r = r0; r < r0 + (B_SZ / 128); ++r) {
        const float v = (float)h16[(size_t)r * D_SZ + d];
        s += v; sq += v * v;
    }
    part[blk * 512 + d]       = s;
    part[blk * 512 + 256 + d] = sq;
}

__global__ __launch_bounds__(256) void bn_finalize(
    const float* __restrict__ part, const float* __restrict__ gamma, const float* __restrict__ beta,
    float* __restrict__ scale, float* __restrict__ shift)
{
    const int d = threadIdx.x;
    float s = 0.f, sq = 0.f;
    for (int b = 0; b < 128; ++b) { s += part[b * 512 + d]; sq += part[b * 512 + 256 + d]; }
    const float mu  = s / (float)B_SZ;
    const float var = sq / (float)B_SZ - mu * mu;
    const float sc  = gamma[d] * rsqrtf(var + BN_EPS);
    scale[d] = sc;
    shift[d] = beta[d] - mu * sc;
}

extern "C" void kernel_launch(void* const* d_in, const int* in_sizes, int n_in,
                              void* d_out, int out_size, void* d_ws, size_t ws_size,
                              hipStream_t stream)
{
    const float* x     = (const float*)d_in[0];
    const float* u     = (const float*)d_in[1];
    const float* W     = (const float*)d_in[2];
    const float* bias  = (const float*)d_in[3];
    const float* gamma = (const float*)d_in[4];
    const float* beta  = (const float*)d_in[5];
    const float* E     = (const float*)d_in[6];

    float* probs = (float*)d_out;                       // [B, K] f32
    float* z     = probs + (size_t)B_SZ * K_CB;         // [B, D] f32

    char* ws = (char*)d_ws;
    f16* assign16 = (f16*)ws;  ws += (size_t)B_SZ * K_CB * 2;     // 32MB
    f16* h16 = (f16*)ws;       ws += (size_t)B_SZ * D_SZ * 2;     // 4MB
    f16* WT16 = (f16*)ws;      ws += (size_t)D_SZ * IN_DIM * 2;   // 0.5MB
    f16* E16 = (f16*)ws;       ws += (size_t)K_CB * D_SZ * 2;     // 1MB
    f16* ET16 = (f16*)ws;      ws += (size_t)D_SZ * K_CB * 2;     // 1MB
    float* part = (float*)ws;  ws += 128 * 512 * 4;
    float* scale = (float*)ws; ws += D_SZ * 4;
    float* shift = (float*)ws; ws += D_SZ * 4;
    float* e2 = (float*)ws;    ws += K_CB * 4;

    // prep: tiled-transpose f16 operands (coalesced both sides) + norms
    {
        dim3 gW(IN_DIM / 64, D_SZ / 64);     // W [1024][256] -> WT16 [256][1024]
        transp_f16<false><<<gW, 256, 0, stream>>>(W, WT16, nullptr, IN_DIM, D_SZ);
        dim3 gE(K_CB / 64, D_SZ / 64);       // E [2048][256] -> ET16 [256][2048] + E16
        transp_f16<true><<<gE, 256, 0, stream>>>(E, ET16, E16, K_CB, D_SZ);
    }
    e2_kernel<<<K_CB / 4, 256, 0, stream>>>(E, e2);

    // 1) h16 = f16(x @ W + b)  (raw, pre-BN)   M=8192 N=256 K=1024
    {
        dim3 g(B_SZ / 64, D_SZ / 64);
        gemm_mfma<64, 64, 64, 1, true><<<g, 256, 0, stream>>>(
            x, IN_DIM, WT16, IN_DIM, h16, D_SZ, IN_DIM, bias);
    }
    // 2) BN stats -> scale/shift (normalize folded into fused_sm A-load)
    bn_partial<<<128, 256, 0, stream>>>(h16, part);
    bn_finalize<<<1, 256, 0, stream>>>(part, gamma, beta, scale, shift);

    // 3) fused BN + logits-GEMM + dual softmax -> probs (f32) + assign (f16)
    fused_sm<<<B_SZ / 32, 1024, 0, stream>>>(h16, E16, e2, u, scale, shift, probs, assign16);

    // 4) z = assign @ E                   M=8192 N=256 K=2048, 512 blocks
    {
        dim3 g(B_SZ / 64, D_SZ / 64);
        gemm_mfma<64, 64, 128, 0, false><<<g, 256, 0, stream>>>(
            assign16, K_CB, ET16, K_CB, z, D_SZ, K_CB, nullptr);
    }
}